// Round 10
// baseline (247.176 us; speedup 1.0000x reference)
//
#include <hip/hip_runtime.h>
#include <stdint.h>

#define Bz 2
#define Sz 2048
#define Dz 1024
#define Hz 16
#define HDz 64
#define Mz (Bz*Sz)   // 4096

typedef unsigned short u16;
typedef __attribute__((ext_vector_type(8))) __bf16 bf16x8;
typedef __attribute__((ext_vector_type(4))) __bf16 bf16x4;
typedef __attribute__((ext_vector_type(8))) unsigned short u16x8;
typedef __attribute__((ext_vector_type(4))) unsigned short u16x4;
typedef __attribute__((ext_vector_type(4))) float f32x4;
typedef __attribute__((ext_vector_type(4))) short s16x4;

#define C1 0.1803368801111243f   /* 0.125 * log2(e) */

__device__ __forceinline__ u16 f2bf(float f) {
  union { float f; unsigned u; } v; v.f = f;
  unsigned r = v.u + 0x7fffu + ((v.u >> 16) & 1u);
  return (u16)(r >> 16);
}

__device__ __forceinline__ void async16(void* lds, const void* g) {
  __builtin_amdgcn_global_load_lds(
      (const __attribute__((address_space(1))) unsigned int*)g,
      (__attribute__((address_space(3))) unsigned int*)lds, 16, 0, 0);
}

// ---------- merged preproc: grid (n4/256, 4). role<3 = fp32->bf16 q/k/v; role==3 =
// weight transpose+cvt, weight = blockIdx.x>>10, tile = blockIdx.x&1023 (no idle blocks).
__global__ void __launch_bounds__(256)
prep_kernel(const float* __restrict__ q, const float* __restrict__ k,
            const float* __restrict__ v,
            const float* __restrict__ w0, const float* __restrict__ w1,
            const float* __restrict__ w2, const float* __restrict__ w3,
            u16* __restrict__ xq, u16* __restrict__ xk, u16* __restrict__ xv,
            u16* __restrict__ Wt, int n4) {
  __shared__ __align__(16) float t[32][33];
  const int role = blockIdx.y;
  if (role < 3) {
    const float* in = role == 0 ? q : role == 1 ? k : v;
    u16* out = role == 0 ? xq : role == 1 ? xk : xv;
    int i = blockIdx.x * 256 + threadIdx.x;
    if (i < n4) {
      float4 f = ((const float4*)in)[i];
      ((ushort4*)out)[i] = make_ushort4(f2bf(f.x), f2bf(f.y), f2bf(f.z), f2bf(f.w));
    }
  } else {
    const int z = blockIdx.x >> 10;            // weight index 0..3
    const int tile = blockIdx.x & 1023;        // 32x32 tile grid
    const float* W = z == 0 ? w0 : z == 1 ? w1 : z == 2 ? w2 : w3;
    u16* o = Wt + (size_t)z * Dz * Dz;
    const int n0 = (tile & 31) * 32, k0 = (tile >> 5) * 32;
    const int x = threadIdx.x & 31, y = threadIdx.x >> 5;   // (32,8)
#pragma unroll
    for (int i = 0; i < 4; ++i)
      t[y + i*8][x] = W[(size_t)(k0 + y + i*8) * Dz + n0 + x];
    __syncthreads();
#pragma unroll
    for (int i = 0; i < 4; ++i)
      o[(size_t)(n0 + y + i*8) * Dz + k0 + x] = f2bf(t[x][y + i*8]);
  }
}

// -------- fused QKV GEMM: 128x128 tile, T3-minimal 2-phase prefetch --------
// Double-buffered LDS; per K-iter: issue gload_lds for tile t+1 into buf[cur^1]
// FIRST, then ds_read+MFMA tile t from buf[cur], then ONE __syncthreads() (its
// compiler-emitted vmcnt(0) drain lands AFTER compute -> HBM latency hidden).
// Race-safe: buf[cur^1]'s readers (tile t-1) all finished at the prior barrier.
// Conflict-free fragment reads via both-sides XOR swizzle (R9). XCD remap (R8).
__global__ void __launch_bounds__(256)
gemm_qkv(const u16* __restrict__ xq, const u16* __restrict__ xk, const u16* __restrict__ xv,
         const u16* __restrict__ Wt3,
         const float* __restrict__ bq, const float* __restrict__ bk, const float* __restrict__ bv,
         u16* __restrict__ Qp, u16* __restrict__ Kp, u16* __restrict__ Vp)
{
  __shared__ __align__(16) u16 lA[2][128][32];
  __shared__ __align__(16) u16 lB[2][128][32];
  const int f = blockIdx.x + 24 * blockIdx.y;      // 0..767
  const int xcd = f & 7, tt = f >> 3;              // tt 0..95
  const int nsel = xcd * 3 + (tt % 3);             // 0..23, fixed XCD per nsel
  const int m0 = (tt / 3) * 128;                   // 0..31 -> m tile
  const int sel = nsel >> 3;
  const int n0 = (nsel & 7) * 128;
  const u16* A = sel == 0 ? xq : sel == 1 ? xk : xv;
  const u16* Bt = Wt3 + (size_t)sel * Dz * Dz;
  const float* bias = sel == 0 ? bq : sel == 1 ? bk : bv;
  u16* Cv = sel == 0 ? Qp : sel == 1 ? Kp : Vp;
  const float cs = sel == 0 ? C1 : 1.0f;

  const int tid = threadIdx.x;
  const int w = tid >> 6, lane = tid & 63;
  const int wm = (w >> 1) * 64, wn = (w & 1) * 64;
  const int l16 = lane & 15, qd = lane >> 4;
  const int swr = (l16 >> 1) & 3;                  // read-side swizzle (lane-const)

  f32x4 acc[4][4];
#pragma unroll
  for (int i = 0; i < 4; ++i)
#pragma unroll
    for (int j = 0; j < 4; ++j) acc[i][j] = (f32x4){0.f, 0.f, 0.f, 0.f};

  const int r0 = tid >> 2, r1 = r0 + 64;
  const int c0s = (((tid & 3) ^ ((r0 >> 1) & 3)) * 8);  // source-side swizzled col
  const int c0 = (tid & 3) * 8;                         // linear dest col

  // prologue: stage tile 0 into buf 0
  async16(&lA[0][r0][c0], A  + (size_t)(m0 + r0) * Dz + c0s);
  async16(&lB[0][r0][c0], Bt + (size_t)(n0 + r0) * Dz + c0s);
  async16(&lA[0][r1][c0], A  + (size_t)(m0 + r1) * Dz + c0s);
  async16(&lB[0][r1][c0], Bt + (size_t)(n0 + r1) * Dz + c0s);
  __syncthreads();

  int cur = 0;
  for (int t = 0; t < Dz / 32; ++t) {
    if (t + 1 < Dz / 32) {
      const int k1 = (t + 1) * 32;
      async16(&lA[cur ^ 1][r0][c0], A  + (size_t)(m0 + r0) * Dz + k1 + c0s);
      async16(&lB[cur ^ 1][r0][c0], Bt + (size_t)(n0 + r0) * Dz + k1 + c0s);
      async16(&lA[cur ^ 1][r1][c0], A  + (size_t)(m0 + r1) * Dz + k1 + c0s);
      async16(&lB[cur ^ 1][r1][c0], Bt + (size_t)(n0 + r1) * Dz + k1 + c0s);
    }
    bf16x8 af[4], bfv[4];
#pragma unroll
    for (int t4 = 0; t4 < 4; ++t4) {
      af[t4]  = *(const bf16x8*)&lA[cur][wm + t4 * 16 + l16][(qd ^ swr) * 8];
      bfv[t4] = *(const bf16x8*)&lB[cur][wn + t4 * 16 + l16][(qd ^ swr) * 8];
    }
#pragma unroll
    for (int mt = 0; mt < 4; ++mt)
#pragma unroll
      for (int nt = 0; nt < 4; ++nt)
        acc[mt][nt] = __builtin_amdgcn_mfma_f32_16x16x32_bf16(af[mt], bfv[nt], acc[mt][nt], 0, 0, 0);
    __syncthreads();   // single barrier/iter: drains next-tile loads AFTER compute
    cur ^= 1;
  }

#pragma unroll
  for (int nt = 0; nt < 4; ++nt) {
    const int n = n0 + wn + nt * 16 + l16;
    const float bvl = bias[n];
#pragma unroll
    for (int mt = 0; mt < 4; ++mt)
#pragma unroll
      for (int r = 0; r < 4; ++r) {
        const int m = m0 + wm + mt * 16 + qd * 4 + r;
        Cv[(size_t)m * Dz + n] = f2bf((acc[mt][nt][r] + bvl) * cs);
      }
  }
}

// ---- Vp[B*S][D] bf16 -> Vt[B][H][HD][S] bf16 (per-head transpose; R2-proven) ----
__global__ void __launch_bounds__(256)
vtrans_kernel(const u16* __restrict__ Vp, u16* __restrict__ Vt) {
  __shared__ __align__(16) u16 t[64][72];
  int s0 = blockIdx.x * 64, bh = blockIdx.y;
  int b = bh >> 4;
  int h = bh & 15;
  int tid = threadIdx.x;
#pragma unroll
  for (int p = 0; p < 4; ++p) {
    int c = p * 256 + tid;
    int row = c >> 4, off = (c & 15) * 4;
    ushort4 v = *(const ushort4*)(Vp + (size_t)(b * Sz + s0 + row) * Dz + h * 64 + off);
    *(ushort4*)&t[row][off] = v;
  }
  __syncthreads();
#pragma unroll
  for (int p = 0; p < 4; ++p) {
    int c = p * 256 + tid;
    int d = c >> 4, sc = (c & 15) * 4;
    ushort4 v = make_ushort4(t[sc + 0][d], t[sc + 1][d], t[sc + 2][d], t[sc + 3][d]);
    *(ushort4*)(Vt + (size_t)(bh * 64 + d) * Sz + s0 + sc) = v;
  }
}

// -------- FC GEMM: 128(M)x64(N) tile, T3-minimal 2-phase prefetch --------
__global__ void __launch_bounds__(256)
gemm_fc(const u16* __restrict__ A, const u16* __restrict__ Bt,
        const float* __restrict__ bias, float* __restrict__ C)
{
  __shared__ __align__(16) u16 lA[2][128][32];
  __shared__ __align__(16) u16 lB[2][64][32];
  const int f = blockIdx.x + 16 * blockIdx.y;      // 0..511
  const int xcd = f & 7, tt = f >> 3;              // tt 0..63
  const int ntile = xcd * 2 + (tt & 1);            // 0..15
  const int m0 = (tt >> 1) * 128;                  // 0..31
  const int n0 = ntile * 64;
  const int tid = threadIdx.x;
  const int w = tid >> 6, lane = tid & 63;
  const int wm = (w >> 1) * 64, wn = (w & 1) * 32;
  const int l16 = lane & 15, qd = lane >> 4;
  const int swr = (l16 >> 1) & 3;                  // read-side swizzle (lane-const)

  f32x4 acc[4][2];
#pragma unroll
  for (int i = 0; i < 4; ++i)
#pragma unroll
    for (int j = 0; j < 2; ++j) acc[i][j] = (f32x4){0.f, 0.f, 0.f, 0.f};

  const int r0 = tid >> 2;
  const int c0s = (((tid & 3) ^ ((r0 >> 1) & 3)) * 8);
  const int c0 = (tid & 3) * 8;

  // prologue: stage tile 0 into buf 0
  async16(&lA[0][r0][c0],      A  + (size_t)(m0 + r0) * Dz + c0s);
  async16(&lA[0][r0 + 64][c0], A  + (size_t)(m0 + r0 + 64) * Dz + c0s);
  async16(&lB[0][r0 & 63][(c0 + ((r0 >> 6) ? 16 : 0)) & 31],  // dummy-balanced? no — keep simple:
          Bt + (size_t)(n0 + (r0 & 63)) * Dz + c0s);
  __syncthreads();

  int cur = 0;
  for (int t = 0; t < Dz / 32; ++t) {
    if (t + 1 < Dz / 32) {
      const int k1 = (t + 1) * 32;
      async16(&lA[cur ^ 1][r0][c0],      A  + (size_t)(m0 + r0) * Dz + k1 + c0s);
      async16(&lA[cur ^ 1][r0 + 64][c0], A  + (size_t)(m0 + r0 + 64) * Dz + k1 + c0s);
      if (r0 < 64)
        async16(&lB[cur ^ 1][r0][c0],    Bt + (size_t)(n0 + r0) * Dz + k1 + c0s);
    }
    bf16x8 af[4], bfv[2];
#pragma unroll
    for (int t4 = 0; t4 < 4; ++t4)
      af[t4] = *(const bf16x8*)&lA[cur][wm + t4 * 16 + l16][(qd ^ swr) * 8];
#pragma unroll
    for (int t4 = 0; t4 < 2; ++t4)
      bfv[t4] = *(const bf16x8*)&lB[cur][wn + t4 * 16 + l16][(qd ^ swr) * 8];
#pragma unroll
    for (int mt = 0; mt < 4; ++mt)
#pragma unroll
      for (int nt = 0; nt < 2; ++nt)
        acc[mt][nt] = __builtin_amdgcn_mfma_f32_16x16x32_bf16(af[mt], bfv[nt], acc[mt][nt], 0, 0, 0);
    __syncthreads();
    cur ^= 1;
  }

#pragma unroll
  for (int nt = 0; nt < 2; ++nt) {
    const int n = n0 + wn + nt * 16 + l16;
    const float bvl = bias[n];
#pragma unroll
    for (int mt = 0; mt < 4; ++mt)
#pragma unroll
      for (int r = 0; r < 4; ++r) {
        const int m = m0 + wm + mt * 16 + qd * 4 + r;
        C[(size_t)m * Dz + n] = acc[mt][nt][r] + bvl;
      }
  }
}

// ---------------- fused flash-style attention (FROZEN at R8 form) ----------------
__global__ void __launch_bounds__(512, 4)
attn_kernel(const u16* __restrict__ Qp, const u16* __restrict__ Kp,
            const u16* __restrict__ Vt, u16* __restrict__ Ao)
{
  __shared__ __align__(16) u16 lK[128][72];     // stride 144 B (≡16 mod 128)
  __shared__ __align__(16) u16 lV[64][136];     // stride 272 B, XOR-swizzled cols

  const int f = blockIdx.x + 16 * blockIdx.y;   // 0..511
  const int xcd = f & 7, j = f >> 3;            // j 0..63
  const int bh = xcd * 4 + (j >> 4);            // 0..31: fixed XCD per head
  const int q0 = (j & 15) * 128;
  const int b = bh >> 4, h = bh & 15;
  const int tid = threadIdx.x, w = tid >> 6, lane = tid & 63;
  const int l16 = lane & 15, qd = lane >> 4;

  const int krow = tid >> 3, kcol = (tid & 7) * 8;    // + p*64 rows (krow 0..63)
  const int vrow = tid >> 4, vcol = (tid & 15) * 8;   // + p*32 rows (vrow 0..31)
  const bool vswW = (vrow >> 3) & 1;                  // write-side involution select
  const int vswR = ((l16 >> 3) & 1) << 2;             // read-side swizzle (lane-const)

  // prefetch tile 0 into registers
  u16x8 kreg[2], vreg[2];
#pragma unroll
  for (int p = 0; p < 2; ++p) {
    kreg[p] = *(const u16x8*)(Kp + (size_t)(b * Sz + p * 64 + krow) * Dz + h * 64 + kcol);
    vreg[p] = *(const u16x8*)(Vt + (size_t)(bh * 64 + p * 32 + vrow) * Sz + vcol);
  }

  // Q fragments in registers (pre-scaled by C1), reused for all kv tiles
  bf16x8 qf[2];
#pragma unroll
  for (int ks = 0; ks < 2; ++ks)
    qf[ks] = *(const bf16x8*)(Qp + (size_t)(b * Sz + q0 + w * 16 + l16) * Dz
                              + h * 64 + ks * 32 + qd * 8);

  f32x4 oacc[4];
#pragma unroll
  for (int j2 = 0; j2 < 4; ++j2) oacc[j2] = (f32x4){0.f, 0.f, 0.f, 0.f};
  float lsum = 0.f;

  for (int t = 0; t < Sz / 128; ++t) {
    __syncthreads();
#pragma unroll
    for (int p = 0; p < 2; ++p) {
      *(u16x8*)&lK[p * 64 + krow][kcol] = kreg[p];
      const u16x8 v = vreg[p];
      u16x8 vs;
#pragma unroll
      for (int i = 0; i < 8; ++i) vs[i] = vswW ? v[i ^ 4] : v[i];
      *(u16x8*)&lV[p * 32 + vrow][vcol] = vs;
    }
    if (t + 1 < Sz / 128) {
      const int kv = (t + 1) * 128;
#pragma unroll
      for (int p = 0; p < 2; ++p) {
        kreg[p] = *(const u16x8*)(Kp + (size_t)(b * Sz + kv + p * 64 + krow) * Dz + h * 64 + kcol);
        vreg[p] = *(const u16x8*)(Vt + (size_t)(bh * 64 + p * 32 + vrow) * Sz + kv + vcol);
      }
    }
    __syncthreads();

    // per 16-s strip: S^T = K @ Q^T ; P = exp2 in-register ; O += P @ V ; lsum += sum(P)
#pragma unroll
    for (int nt = 0; nt < 8; ++nt) {
      const bf16x8 kf0 = *(const bf16x8*)&lK[nt * 16 + l16][qd * 8];
      const bf16x8 kf1 = *(const bf16x8*)&lK[nt * 16 + l16][32 + qd * 8];
      f32x4 st = (f32x4){0.f, 0.f, 0.f, 0.f};
      st = __builtin_amdgcn_mfma_f32_16x16x32_bf16(kf0, qf[0], st, 0, 0, 0);
      st = __builtin_amdgcn_mfma_f32_16x16x32_bf16(kf1, qf[1], st, 0, 0, 0);
      const float e0 = exp2f(st[0]), e1 = exp2f(st[1]);
      const float e2 = exp2f(st[2]), e3 = exp2f(st[3]);
      lsum += (e0 + e1) + (e2 + e3);
      bf16x4 pb;
      pb[0] = (__bf16)e0; pb[1] = (__bf16)e1; pb[2] = (__bf16)e2; pb[3] = (__bf16)e3;
      const s16x4 pf = __builtin_bit_cast(s16x4, pb);
#pragma unroll
      for (int nd = 0; nd < 4; ++nd) {
        const s16x4 vf = *(const s16x4*)&lV[nd * 16 + l16][(nt * 16 + qd * 4) ^ vswR];
        oacc[nd] = __builtin_amdgcn_mfma_f32_16x16x16bf16_1k(pf, vf, oacc[nd], 0, 0, 0);
      }
    }
  }

  // rowsum finalize + normalize + store
  lsum += __shfl_xor(lsum, 16, 64);
  lsum += __shfl_xor(lsum, 32, 64);
#pragma unroll
  for (int r = 0; r < 4; ++r) {
    const float inv = 1.0f / __shfl(lsum, qd * 4 + r, 64);
    const int row = q0 + w * 16 + qd * 4 + r;
#pragma unroll
    for (int nd = 0; nd < 4; ++nd) {
      const int col = h * 64 + nd * 16 + l16;
      Ao[(size_t)(b * Sz + row) * Dz + col] = f2bf(oacc[nd][r] * inv);
    }
  }
}

// ---------------- host launch ----------------
extern "C" void kernel_launch(void* const* d_in, const int* in_sizes, int n_in,
                              void* d_out, int out_size, void* d_ws, size_t ws_size,
                              hipStream_t stream) {
  const float* query = (const float*)d_in[0];
  const float* key   = (const float*)d_in[1];
  const float* value = (const float*)d_in[2];
  const float* w_q  = (const float*)d_in[3];
  const float* b_q  = (const float*)d_in[4];
  const float* w_k  = (const float*)d_in[5];
  const float* b_k  = (const float*)d_in[6];
  const float* w_v  = (const float*)d_in[7];
  const float* b_v  = (const float*)d_in[8];
  const float* w_fc = (const float*)d_in[9];
  const float* b_fc = (const float*)d_in[10];
  float* out = (float*)d_out;

  const size_t XE = (size_t)Mz * Dz;   // 4 Mi elements
  const size_t WE = (size_t)Dz * Dz;   // 1 Mi elements
  u16* Xq  = (u16*)d_ws;               // bf16 inputs
  u16* Xk  = Xq + XE;
  u16* Xv  = Xk + XE;
  u16* Wt  = Xv + XE;                  // 4 stacked transposed weights [N][K]: q,k,v,fc
  u16* Wtf = Wt + 3 * WE;
  u16* Qp  = Wt + 4 * WE;              // projections
  u16* Kp  = Qp + XE;
  u16* Vp  = Kp + XE;
  u16* Vt  = Xk;                       // reuse: Xk dead after QKV projections
  u16* Ao  = Xq;                       // reuse: Xq dead after QKV projections

  const int n4 = (int)(XE / 4);
  prep_kernel<<<dim3(n4 / 256, 4), 256, 0, stream>>>(query, key, value,
                                                     w_q, w_k, w_v, w_fc,
                                                     Xq, Xk, Xv, Wt, n4);

  gemm_qkv<<<dim3(24, Mz / 128), 256, 0, stream>>>(Xq, Xk, Xv, Wt, b_q, b_k, b_v, Qp, Kp, Vp);

  vtrans_kernel<<<dim3(Sz / 64, Bz * Hz), 256, 0, stream>>>(Vp, Vt);

  attn_kernel<<<dim3(Sz / 128, Bz * Hz), 512, 0, stream>>>(Qp, Kp, Vt, Ao);

  gemm_fc<<<dim3(Dz / 64, Mz / 128), 256, 0, stream>>>(Ao, Wtf, b_fc, out);
}